// Round 6
// baseline (120.491 us; speedup 1.0000x reference)
//
#include <hip/hip_runtime.h>
#include <math.h>

#define NB 2
#define LL 4096
#define HH 1024
#define DD 64
#define CHK 64
#define NCH 64            /* LL/CHK */
#define BLROWS (NB*LL)    /* 8192 */
#define NCHT (NB*NCH)     /* 128 total chunks */
#define GAMMA 0.96875f

typedef _Float16 f16x8 __attribute__((ext_vector_type(8)));
typedef _Float16 f16x4 __attribute__((ext_vector_type(4)));
typedef float    f32x4 __attribute__((ext_vector_type(4)));

#define WCH 12288   /* W frag layout: [16 kchunks][12 ct][2 kt][64 lanes][8] */

// ---------------------------------------------------------------------------
// Kernel 0: split W (scaled 2^10) into fp16 hi/lo, fragment order.
// grid 96 x 256 (24576 f16x8 slots), coalesced stores.
// ---------------------------------------------------------------------------
__global__ __launch_bounds__(256) void prep_w(
    const float* __restrict__ WQ, const float* __restrict__ WK,
    const float* __restrict__ WV, _Float16* __restrict__ Whg,
    _Float16* __restrict__ Wlg)
{
    const unsigned t = blockIdx.x * 256 + threadIdx.x;   // 0..24575
    const unsigned kchunk = t / 1536u;
    const unsigned s = t - kchunk * 1536u;
    const int ct2  = s >> 6;            // (n16)*2 + kt
    const int lane = s & 63;
    const int n16  = ct2 >> 1;
    const int kt   = ct2 & 1;
    const int quad = lane >> 4;
    const int n    = n16 * 16 + (lane & 15);
    const int k0   = (int)kchunk * 64 + kt * 32 + quad * 8;
    const int m    = n >> 6;
    const int d    = n & 63;
    const float* Wm = (m == 0) ? WQ : (m == 1) ? WK : WV;
    f16x8 hv, lv;
#pragma unroll
    for (int j = 0; j < 8; ++j) {
        const float x = Wm[(size_t)(k0 + j) * DD + d] * 1024.f;
        const _Float16 h = (_Float16)x;
        hv[j] = h;
        lv[j] = (_Float16)(x - (float)h);
    }
    *(f16x8*)&Whg[(size_t)t * 8] = hv;
    *(f16x8*)&Wlg[(size_t)t * 8] = lv;
}

// ---------------------------------------------------------------------------
// Kernel 1: MFMA projection, BARRIER-FREE (no LDS):
//   B-frags read directly from fragment-ordered Whg/Wlg (16 B/lane coalesced);
//   A-frags read directly from row-major fp32 X, hi/lo split in-register.
// grid 256 x 256 (4 waves). Block = 32 rows x 192 cols; wave wv owns coltiles
// 3wv..3wv+2 and both rowtiles. fp16 split-3 products, fp32 acc.
// ---------------------------------------------------------------------------
__global__ __launch_bounds__(256) void proj_mfma(
    const float* __restrict__ X, const _Float16* __restrict__ Whg,
    const _Float16* __restrict__ Wlg, _Float16* __restrict__ Qr,
    _Float16* __restrict__ Kr, _Float16* __restrict__ Vr)
{
    const int tid  = threadIdx.x;
    const int wv   = tid >> 6;
    const int lane = tid & 63;
    const int quad = lane >> 4;
    const int l15  = lane & 15;
    const int r0   = blockIdx.x * 32;

    f32x4 acc[6];
#pragma unroll
    for (int i = 0; i < 6; ++i) acc[i] = (f32x4){0.f, 0.f, 0.f, 0.f};

    for (int ch = 0; ch < 16; ++ch) {
        // ---- A-frags straight from X (fp32), split hi/lo in-register ----
        f16x8 ah[2][2], al[2][2];
#pragma unroll
        for (int rt = 0; rt < 2; ++rt) {
#pragma unroll
            for (int kt = 0; kt < 2; ++kt) {
                const float* xp = &X[(size_t)(r0 + rt * 16 + l15) * HH +
                                     ch * 64 + kt * 32 + quad * 8];
                const float4 xa = *(const float4*)&xp[0];
                const float4 xb = *(const float4*)&xp[4];
                const float xv[8] = {xa.x, xa.y, xa.z, xa.w,
                                     xb.x, xb.y, xb.z, xb.w};
                f16x8 hv, lv;
#pragma unroll
                for (int e = 0; e < 8; ++e) {
                    const _Float16 h = (_Float16)xv[e];
                    hv[e] = h;
                    lv[e] = (_Float16)(xv[e] - (float)h);
                }
                ah[rt][kt] = hv;
                al[rt][kt] = lv;
            }
        }
        // ---- B-frags straight from fragment-ordered W; MFMA ----
#pragma unroll
        for (int kt = 0; kt < 2; ++kt) {
#pragma unroll
            for (int cj = 0; cj < 3; ++cj) {
                const int ctg = wv * 3 + cj;
                const size_t off = (size_t)ch * WCH +
                                   (size_t)(((ctg * 2 + kt) * 64 + lane)) * 8;
                const f16x8 bh = *(const f16x8*)&Whg[off];
                const f16x8 bl = *(const f16x8*)&Wlg[off];
#pragma unroll
                for (int rt = 0; rt < 2; ++rt) {
                    acc[rt * 3 + cj] = __builtin_amdgcn_mfma_f32_16x16x32_f16(
                        ah[rt][kt], bh, acc[rt * 3 + cj], 0, 0, 0);
                    acc[rt * 3 + cj] = __builtin_amdgcn_mfma_f32_16x16x32_f16(
                        ah[rt][kt], bl, acc[rt * 3 + cj], 0, 0, 0);
                    acc[rt * 3 + cj] = __builtin_amdgcn_mfma_f32_16x16x32_f16(
                        al[rt][kt], bh, acc[rt * 3 + cj], 0, 0, 0);
                }
            }
        }
    }

    // ---- epilogue: descale + xPos (per-chunk renormalized scale), fp16 out
    const int c16 = l15;
#pragma unroll
    for (int rt = 0; rt < 2; ++rt) {
#pragma unroll
        for (int cj = 0; cj < 3; ++cj) {
            const int ctg = wv * 3 + cj;
            const f32x4 v = acc[rt * 3 + cj];
            const int col = ctg * 16 + c16;
            const int mat = ctg >> 2;            // 0=Q 1=K 2=V
            const int d   = col & 63;
            if (mat < 2) {
                const int i2 = d >> 1;
                const float sv   = (2.f * (float)i2 + 25.6f) / 89.6f;
                const float l2sv = log2f(sv);
                const float ifr  = exp2f(-13.28771237954945f * ((float)i2 / 32.f));
                const float sgn  = (mat == 0) ? 1.f : -1.f;
                _Float16* dst = (mat == 0) ? Qr : Kr;
#pragma unroll
                for (int r = 0; r < 4; ++r) {
                    const int row = r0 + rt * 16 + quad * 4 + r;
                    const float val = v[r] * (1.f / 1024.f);
                    const float p = __shfl_xor(val, 1, 64);
                    const float pf  = (float)(row & (LL - 1));   // abs pos
                    const float pfs = (float)(row & 63);          // renorm
                    const float scl = exp2f(sgn * (pfs * (1.f / 512.f)) * l2sv);
                    float s, c;
                    sincosf(pf * ifr, &s, &c);
                    s *= scl; c *= scl;
                    const float o = ((col & 1) == 0) ? val * c - p * s
                                                     : val * c + p * s;
                    dst[(size_t)row * DD + d] = (_Float16)o;
                }
            } else {
#pragma unroll
                for (int r = 0; r < 4; ++r) {
                    const int row = r0 + rt * 16 + quad * 4 + r;
                    Vr[(size_t)row * DD + d] = (_Float16)(v[r] * (1.f / 1024.f));
                }
            }
        }
    }
}

// ---------------------------------------------------------------------------
// Kernel 2: U~[chunk][d][d'] = sum_j g^(63-j) K~[j][d] V[j][d']  (fp32 out)
// grid 256 = (chunk 128) x (d'-half 2), 256 thr.
// ---------------------------------------------------------------------------
__global__ __launch_bounds__(256) void chunk_kv(
    const _Float16* __restrict__ Kr, const _Float16* __restrict__ Vr,
    float* __restrict__ U)
{
    __shared__ _Float16 Kl[64 * 64];
    __shared__ _Float16 Vl[64 * 32];
    __shared__ float pwd[64];
    const int tid   = threadIdx.x;
    const int bc    = blockIdx.x;
    const int chunk = bc >> 1;
    const int dph   = (bc & 1) * 32;
    const size_t rbase = (size_t)chunk * CHK * DD;
    const float l2g = log2f(GAMMA);

    if (tid < 64) pwd[tid] = exp2f((float)(63 - tid) * l2g);
    {
        const int row = tid >> 2;
        const int c0  = (tid & 3) * 16;
        *(f16x8*)&Kl[row * 64 + c0]     = *(const f16x8*)&Kr[rbase + (size_t)row * DD + c0];
        *(f16x8*)&Kl[row * 64 + c0 + 8] = *(const f16x8*)&Kr[rbase + (size_t)row * DD + c0 + 8];
        const int c1 = (tid & 3) * 8;
        *(f16x8*)&Vl[row * 32 + c1] = *(const f16x8*)&Vr[rbase + (size_t)row * DD + dph + c1];
    }
    __syncthreads();
    const int dgr = tid >> 4;
    const int dc  = tid & 15;
    float a[4][2] = {{0,0},{0,0},{0,0},{0,0}};
#pragma unroll 8
    for (int j = 0; j < CHK; ++j) {
        const f16x4 kh = *(const f16x4*)&Kl[j * 64 + dgr * 4];
        const float w  = pwd[j];
        const float v0 = (float)Vl[j * 32 + dc * 2]     * w;
        const float v1 = (float)Vl[j * 32 + dc * 2 + 1] * w;
        const float k0 = (float)kh[0], k1 = (float)kh[1];
        const float k2 = (float)kh[2], k3 = (float)kh[3];
        a[0][0] += k0 * v0; a[0][1] += k0 * v1;
        a[1][0] += k1 * v0; a[1][1] += k1 * v1;
        a[2][0] += k2 * v0; a[2][1] += k2 * v1;
        a[3][0] += k3 * v0; a[3][1] += k3 * v1;
    }
#pragma unroll
    for (int r = 0; r < 4; ++r) {
        *(float2*)&U[((size_t)chunk * DD + dgr * 4 + r) * DD + dph + dc * 2] =
            make_float2(a[r][0], a[r][1]);
    }
}

// ---------------------------------------------------------------------------
// Kernel 3: chunk output with in-LDS T-build (absorbs old prep_vt).
//   T~_c = sum_{D=1..8} g^{64(D-1)} sv_d^{D/8} U~[c-D]   (in LDS, fp32)
//   phase A: S = mask(Q~ K~^T); S2 = [S | g^{n'+1} Q~] -> LDS (A-frag order)
//   phase B: out = S2 @ [V ; T~]   (B-frags gathered from LDS)
// grid 256 = (chunk 128) x (n-half 2), 256 thr. LDS ~35.6 KB -> 4 blocks/CU.
// ---------------------------------------------------------------------------
__global__ __launch_bounds__(256) void chunk_out(
    const _Float16* __restrict__ Qr, const _Float16* __restrict__ Kr,
    const _Float16* __restrict__ Vr, const float* __restrict__ U,
    float* __restrict__ out)
{
    __shared__ __align__(16) unsigned char smraw[35648];
    _Float16* Sb  = (_Float16*)smraw;            // 32*136 f16 = 8704 B
    _Float16* Vl  = (_Float16*)(smraw + 8704);   // 64*72 f16 = 9216 B
    float*    Tl  = (float*)(smraw + 17920);     // 64*68 f32 = 17408 B
    float*    pwl = (float*)(smraw + 35328);     // 65 f32

    const int tid   = threadIdx.x;
    const int bc    = blockIdx.x;
    const int chunk = bc >> 1;
    const int nh    = (bc & 1) * 32;
    const int w     = tid >> 6;
    const int lane  = tid & 63;
    const int quad  = lane >> 4;
    const int l15   = lane & 15;
    const int mtile = w >> 1;
    const int npair = (w & 1) * 2;
    const size_t rowbase = (size_t)chunk * CHK + nh;
    const float l2g = log2f(GAMMA);

    if (tid < 65) pwl[tid] = exp2f((float)tid * l2g);

    {   // stage V rows
        const int row = tid >> 2;
        const int c0  = (tid & 3) * 16;
        const size_t rb = (size_t)chunk * CHK * DD;
        *(f16x8*)&Vl[row * 72 + c0]     = *(const f16x8*)&Vr[rb + (size_t)row * DD + c0];
        *(f16x8*)&Vl[row * 72 + c0 + 8] = *(const f16x8*)&Vr[rb + (size_t)row * DD + c0 + 8];
    }
    {   // build T~ from 8 preceding U chunks
        const int d  = tid >> 2;
        const int dq = (tid & 3) * 16;
        const int cloc = chunk & 63;
        const float sv = (2.f * (float)(d >> 1) + 25.6f) / 89.6f;
        const float l2sv = log2f(sv);
        float acc[16];
#pragma unroll
        for (int i = 0; i < 16; ++i) acc[i] = 0.f;
        for (int dl = 1; dl <= 8; ++dl) {
            if (dl <= cloc) {
                const float f = exp2f(64.f * (float)(dl - 1) * l2g +
                                      0.125f * (float)dl * l2sv);
                const float* up = &U[((size_t)(chunk - dl) * DD + d) * DD + dq];
#pragma unroll
                for (int i4 = 0; i4 < 4; ++i4) {
                    const float4 u = *(const float4*)&up[i4 * 4];
                    acc[i4 * 4 + 0] += f * u.x; acc[i4 * 4 + 1] += f * u.y;
                    acc[i4 * 4 + 2] += f * u.z; acc[i4 * 4 + 3] += f * u.w;
                }
            }
        }
#pragma unroll
        for (int i = 0; i < 16; ++i) Tl[d * 68 + dq + i] = acc[i];
    }

    // global A/B frags for phase A
    f16x8 aQ[2], bK[2][2];
#pragma unroll
    for (int ks = 0; ks < 2; ++ks)
        aQ[ks] = *(const f16x8*)&Qr[(rowbase + mtile * 16 + l15) * DD +
                                    ks * 32 + quad * 8];
#pragma unroll
    for (int nt = 0; nt < 2; ++nt)
#pragma unroll
        for (int ks = 0; ks < 2; ++ks)
            bK[nt][ks] = *(const f16x8*)&Kr[((size_t)chunk * CHK +
                                            (npair + nt) * 16 + l15) * DD +
                                            ks * 32 + quad * 8];
    __syncthreads();   // Vl, Tl, pwl ready

    f32x4 sA[2] = {(f32x4){0.f,0.f,0.f,0.f}, (f32x4){0.f,0.f,0.f,0.f}};
#pragma unroll
    for (int nt = 0; nt < 2; ++nt)
#pragma unroll
        for (int ks = 0; ks < 2; ++ks)
            sA[nt] = __builtin_amdgcn_mfma_f32_16x16x32_f16(aQ[ks], bK[nt][ks],
                                                            sA[nt], 0, 0, 0);
    // mask + decay -> Sb (A-frag layout, fp16)
#pragma unroll
    for (int nt = 0; nt < 2; ++nt) {
        const int m = (npair + nt) * 16 + l15;
#pragma unroll
        for (int r = 0; r < 4; ++r) {
            const int nl = mtile * 16 + quad * 4 + r;
            const int n64 = nh + nl;
            const float val = (n64 >= m) ? sA[nt][r] * pwl[n64 - m] : 0.f;
            Sb[nl * 136 + m] = (_Float16)val;
        }
    }
    // Q'' columns 64..127 (even waves)
    if ((w & 1) == 0) {
        const float g = pwl[nh + mtile * 16 + l15 + 1];
#pragma unroll
        for (int ks = 0; ks < 2; ++ks) {
            f16x8 qv;
#pragma unroll
            for (int j = 0; j < 8; ++j)
                qv[j] = (_Float16)((float)aQ[ks][j] * g);
            *(f16x8*)&Sb[(mtile * 16 + l15) * 136 + 64 + ks * 32 + quad * 8] = qv;
        }
    }
    __syncthreads();

    // phase B: out = S2 @ [V ; T~]
    f32x4 oA[2] = {(f32x4){0.f,0.f,0.f,0.f}, (f32x4){0.f,0.f,0.f,0.f}};
#pragma unroll
    for (int ks = 0; ks < 4; ++ks) {
        const f16x8 aS = *(const f16x8*)&Sb[(mtile * 16 + l15) * 136 +
                                            ks * 32 + quad * 8];
#pragma unroll
        for (int nt = 0; nt < 2; ++nt) {
            const int dp = (npair + nt) * 16 + l15;
            f16x8 bV;
            if (ks < 2) {
#pragma unroll
                for (int j = 0; j < 8; ++j)
                    bV[j] = Vl[(ks * 32 + quad * 8 + j) * 72 + dp];
            } else {
#pragma unroll
                for (int j = 0; j < 8; ++j)
                    bV[j] = (_Float16)Tl[((ks - 2) * 32 + quad * 8 + j) * 68 + dp];
            }
            oA[nt] = __builtin_amdgcn_mfma_f32_16x16x32_f16(aS, bV, oA[nt], 0, 0, 0);
        }
    }
#pragma unroll
    for (int nt = 0; nt < 2; ++nt)
#pragma unroll
        for (int r = 0; r < 4; ++r)
            out[(rowbase + mtile * 16 + quad * 4 + r) * DD +
                (npair + nt) * 16 + l15] = oA[nt][r];
}

// ---------------------------------------------------------------------------
extern "C" void kernel_launch(void* const* d_in, const int* in_sizes, int n_in,
                              void* d_out, int out_size, void* d_ws, size_t ws_size,
                              hipStream_t stream)
{
    const float* X  = (const float*)d_in[0];
    const float* WQ = (const float*)d_in[1];
    const float* WK = (const float*)d_in[2];
    const float* WV = (const float*)d_in[3];
    float* outp = (float*)d_out;

    _Float16* Whg = (_Float16*)d_ws;                 // 196608 h
    _Float16* Wlg = Whg + 196608;                    // 196608 h
    _Float16* Qr  = Wlg + 196608;                    // 524288 h
    _Float16* Kr  = Qr + (size_t)BLROWS * DD;        // 524288 h
    _Float16* Vr  = Kr + (size_t)BLROWS * DD;        // 524288 h
    float*    U   = (float*)(Vr + (size_t)BLROWS * DD);   // 524288 f
    // total ~6.1 MB

    hipLaunchKernelGGL(prep_w, dim3(96), dim3(256), 0, stream,
                       WQ, WK, WV, Whg, Wlg);
    hipLaunchKernelGGL(proj_mfma, dim3(BLROWS / 32), dim3(256), 0, stream,
                       X, Whg, Wlg, Qr, Kr, Vr);
    hipLaunchKernelGGL(chunk_kv, dim3(2 * NCHT), dim3(256), 0, stream, Kr, Vr, U);
    hipLaunchKernelGGL(chunk_out, dim3(2 * NCHT), dim3(256), 0, stream,
                       Qr, Kr, Vr, U, outp);
}